// Round 9
// baseline (64.079 us; speedup 1.0000x reference)
//
#include <hip/hip_runtime.h>

// Problem constants (from reference setup_inputs)
#define N_  16
#define C_  64
#define H_  128
#define W_  128
#define HO_ 64
#define WO_ 64
#define CO_ 18   // G*K*K = 2*3*3
#define NSP 8          // channel splits (= waves per block)
#define CPS (C_/NSP)   // 8 channels per split
#define WSZ (C_*CO_*9) // 10368 transposed weights

// ws layout: [0 .. 10367] cwT[c*162 + o*9 + k] = cw[o*576+c*9+k] * inv[o]
//            [10368 .. 10385] shift[o] = beta[o] - mean[o]*inv[o]
__global__ void pasa_prep(const float* __restrict__ cw,
                          const float* __restrict__ gamma,
                          const float* __restrict__ beta,
                          const float* __restrict__ mean,
                          const float* __restrict__ var,
                          float* __restrict__ ws)
{
    const int i = blockIdx.x * 256 + threadIdx.x;
    if (i < WSZ) {
        const int k = i % 9;
        const int o = (i / 9) % CO_;
        const int c = i / (9 * CO_);
        const float inv = gamma[o] * rsqrtf(var[o] + 1e-5f);
        ws[c * (CO_*9) + o * 9 + k] = cw[o * (C_*9) + c * 9 + k] * inv;
    }
    if (i < CO_) {
        const float inv = gamma[i] * rsqrtf(var[i] + 1e-5f);
        ws[WSZ + i] = beta[i] - mean[i] * inv;
    }
}

__global__ __launch_bounds__(512)
void pasa_main(const float* __restrict__ x,
               const float* __restrict__ wt,    // = ws (cwT + shift)
               float* __restrict__ out)
{
    // partial logits: [sp][wo][o], o contiguous -> float2 LDS ops (36864 B)
    __shared__ float part[NSP][WO_][CO_];

    const int tid = threadIdx.x;
    const int wo  = tid & 63;          // lane -> output col
    const int sp  = tid >> 6;          // wave id = channel split
    // XCD-chunk swizzle: XCD = bx & 7; each XCD gets 8 contiguous ho rows.
    const int bx  = blockIdx.x;
    const int ho  = ((bx & 7) << 3) | (bx >> 3);
    const int n   = blockIdx.y;

    // 3x3 window at input (2ho, 2wo), reflect pad=1 (only -1 reachable -> +1)
    int r0 = 2*ho - 1; if (r0 < 0) r0 = 1;
    const int r1 = 2*ho, r2 = 2*ho + 1;
    const int c1 = 2*wo;
    int c0 = c1 - 1; if (c0 < 0) c0 = 1;

    const float* __restrict__ xn    = x  + (size_t)n * (C_*H_*W_);
    const float* __restrict__ shift = wt + WSZ;

    float sig[CO_];
#pragma unroll
    for (int o = 0; o < CO_; ++o) sig[o] = 0.f;

    // Pass 1: j-outer conv. Per channel: 9 window loads (VMEM), then 162 FMA
    // against 162 CONTIGUOUS scalar-loaded weights (wide s_load_dwordx16,
    // prefetchable one j ahead). Only ~9 window floats live at a time.
#pragma unroll
    for (int j = 0; j < CPS; ++j) {
        const int c = __builtin_amdgcn_readfirstlane(sp * CPS + j);
        const float* __restrict__ xc = xn + c * (H_*W_);
        const float  w0  = xc[r0*W_ + c0];
        float2 t01 = *(const float2*)(xc + r0*W_ + c1);   // 8B aligned
        const float  w3  = xc[r1*W_ + c0];
        float2 t45 = *(const float2*)(xc + r1*W_ + c1);
        const float  w6  = xc[r2*W_ + c0];
        float2 t78 = *(const float2*)(xc + r2*W_ + c1);
        const float* __restrict__ q = wt + c * (CO_*9);   // 162 contiguous
#pragma unroll
        for (int o = 0; o < CO_; ++o) {
            float a = sig[o];
            a = fmaf(w0,    q[o*9 + 0], a);
            a = fmaf(t01.x, q[o*9 + 1], a);
            a = fmaf(t01.y, q[o*9 + 2], a);
            a = fmaf(w3,    q[o*9 + 3], a);
            a = fmaf(t45.x, q[o*9 + 4], a);
            a = fmaf(t45.y, q[o*9 + 5], a);
            a = fmaf(w6,    q[o*9 + 6], a);
            a = fmaf(t78.x, q[o*9 + 7], a);
            a = fmaf(t78.y, q[o*9 + 8], a);
            sig[o] = a;
        }
    }

    // Tree-reduce the 8 wave partials through LDS (float2 granularity).
#pragma unroll
    for (int i = 0; i < 9; ++i)
        *(float2*)&part[sp][wo][2*i] = make_float2(sig[2*i], sig[2*i+1]);
    __syncthreads();
    if (sp < 4) {
#pragma unroll
        for (int i = 0; i < 9; ++i) {
            const float2 a = *(const float2*)&part[sp+4][wo][2*i];
            float2* d = (float2*)&part[sp][wo][2*i];
            float2 b = *d; b.x += a.x; b.y += a.y; *d = b;
        }
    }
    __syncthreads();
    if (sp < 2) {
#pragma unroll
        for (int i = 0; i < 9; ++i) {
            const float2 a = *(const float2*)&part[sp+2][wo][2*i];
            float2* d = (float2*)&part[sp][wo][2*i];
            float2 b = *d; b.x += a.x; b.y += a.y; *d = b;
        }
    }
    __syncthreads();
    if (sp == 0) {
#pragma unroll
        for (int i = 0; i < 9; ++i) {
            const float2 a = *(const float2*)&part[1][wo][2*i];
            float2* d = (float2*)&part[0][wo][2*i];
            float2 b = *d; b.x += a.x; b.y += a.y; *d = b;
        }
    }
    __syncthreads();

    // Final logits (+BN shift) + softmax over 18, redundant per thread.
    float mx = -3.4e38f;
#pragma unroll
    for (int i = 0; i < 9; ++i) {
        const float2 a = *(const float2*)&part[0][wo][2*i];
        sig[2*i]   = a.x + shift[2*i];
        sig[2*i+1] = a.y + shift[2*i+1];
    }
#pragma unroll
    for (int o = 0; o < CO_; ++o) mx = fmaxf(mx, sig[o]);
    float sum = 0.f;
#pragma unroll
    for (int o = 0; o < CO_; ++o) { sig[o] = __expf(sig[o] - mx); sum += sig[o]; }
    const float rs = 1.f / sum;

    // Group-select with compile-time sig[] indices (g = sp>>2 is wave-uniform)
    float p[9];
    if ((sp >> 2) == 0) {
#pragma unroll
        for (int k = 0; k < 9; ++k) p[k] = sig[k] * rs;
    } else {
#pragma unroll
        for (int k = 0; k < 9; ++k) p[k] = sig[9 + k] * rs;
    }

    // Pass 2: aggregation; windows re-loaded (L1-hot from pass 1).
#pragma unroll
    for (int j = 0; j < CPS; ++j) {
        const int c = sp * CPS + j;
        const float* __restrict__ xc = xn + c * (H_*W_);
        float acc = xc[r0*W_ + c0] * p[0];
        const float2 a12 = *(const float2*)(xc + r0*W_ + c1);
        acc = fmaf(a12.x, p[1], acc);
        acc = fmaf(a12.y, p[2], acc);
        acc = fmaf(xc[r1*W_ + c0], p[3], acc);
        const float2 a45 = *(const float2*)(xc + r1*W_ + c1);
        acc = fmaf(a45.x, p[4], acc);
        acc = fmaf(a45.y, p[5], acc);
        acc = fmaf(xc[r2*W_ + c0], p[6], acc);
        const float2 a78 = *(const float2*)(xc + r2*W_ + c1);
        acc = fmaf(a78.x, p[7], acc);
        acc = fmaf(a78.y, p[8], acc);
        out[(((size_t)n*C_ + c)*HO_ + ho)*WO_ + wo] = acc;
    }
}

extern "C" void kernel_launch(void* const* d_in, const int* in_sizes, int n_in,
                              void* d_out, int out_size, void* d_ws, size_t ws_size,
                              hipStream_t stream) {
    const float* x     = (const float*)d_in[0];
    const float* cw    = (const float*)d_in[1];
    const float* gamma = (const float*)d_in[2];
    const float* beta  = (const float*)d_in[3];
    const float* mean  = (const float*)d_in[4];
    const float* var   = (const float*)d_in[5];
    float* out = (float*)d_out;
    float* ws  = (float*)d_ws;   // needs (10368+18)*4 B

    pasa_prep<<<(WSZ + 255) / 256, 256, 0, stream>>>(cw, gamma, beta, mean, var, ws);
    dim3 grid(HO_, N_);   // 64 ho-rows x 16 batch, 8 waves/block
    pasa_main<<<grid, 512, 0, stream>>>(x, ws, out);
}